// Round 4
// baseline (85.648 us; speedup 1.0000x reference)
//
#include <hip/hip_runtime.h>
#include <hip/hip_bf16.h>

// x: [4, 4096, 4096] f32, W1: [48, 4096] f32, W2: [48, 48] f32
// out: [4, 4, 4096, 12] f32  (C, B, T, L/C)
#define DDIM 4096
#define LTOT 48

typedef __attribute__((ext_vector_type(4))) float f32x4;
typedef __attribute__((ext_vector_type(8))) short bf16x8;

__device__ __forceinline__ unsigned cvt_pk(float x, float y) {
    union { __hip_bfloat162 h; unsigned u; } c;
    c.h = __float22bfloat162_rn(make_float2(x, y));
    return c.u;
}

// ---- kernel 0: W1 fp32 -> bf16 (RNE) into workspace ----
__global__ void w1cvt_kernel(const float* __restrict__ w1, ushort* __restrict__ w1b) {
    int i = blockIdx.x * 256 + threadIdx.x;
    union { float f; unsigned u; } v; v.f = w1[i];
    unsigned r = v.u + 0x7fffu + ((v.u >> 16) & 1u);
    w1b[i] = (ushort)(r >> 16);
}

// ---- fused: pure-register 2-deep streaming, sumsq + x@W1^T + rms + gelu
//      + @W2^T + transposed store. 4 waves/block, K-split 1024 each. ----
__global__ __launch_bounds__(256, 4) void fused_kernel(
        const float* __restrict__ x,
        const ushort* __restrict__ w1b,
        const float* __restrict__ w2,
        float* __restrict__ out) {
    __shared__ float dots[4][16][48];
    __shared__ float ssw[4][16];
    __shared__ float scl[16];
    __shared__ float gbuf[16][48];
    __shared__ float w2s[LTOT * LTOT];

    const int tid  = threadIdx.x;
    const int wave = tid >> 6;
    const int lane = tid & 63;
    const int rl   = lane & 15;   // A-row / B-row / C-col
    const int kg   = lane >> 4;   // k-group 0..3
    const int row0 = blockIdx.x * 16;
    const int kw   = wave * 1024; // per-wave K range

    // per-lane bases in MFMA fragment layout (k = kg*8 + j within each K=32)
    const float*  xp = x   + (size_t)(row0 + rl) * DDIM + kw + kg * 8;
    const ushort* bp = w1b + (size_t)rl * DDIM          + kw + kg * 8;

    // A chunk c = K window [c*64, +64): 4 x 16B contiguous-pair loads
    auto loadA = [&](int c, f32x4 (&A)[2][2]) {
        const float* p = xp + c * 64;
        #pragma unroll
        for (int h = 0; h < 2; ++h) {
            A[h][0] = *(const f32x4*)(p + h * 32);
            A[h][1] = *(const f32x4*)(p + h * 32 + 4);
        }
    };
    // B chunk c: 6 x 16B bf16 fragments (L2-resident W1b)
    auto loadB = [&](int c, bf16x8 (&Bv)[6]) {
        const ushort* p = bp + c * 64;
        #pragma unroll
        for (int n = 0; n < 3; ++n)
            #pragma unroll
            for (int h = 0; h < 2; ++h)
                Bv[n * 2 + h] = *(const bf16x8*)(p + n * 16 * DDIM + h * 32);
    };

    f32x4 acc[3] = {{0.f,0.f,0.f,0.f},{0.f,0.f,0.f,0.f},{0.f,0.f,0.f,0.f}};
    float ss = 0.f;

    auto compute = [&](f32x4 (&A)[2][2], bf16x8 (&Bv)[6]) {
        #pragma unroll
        for (int h = 0; h < 2; ++h) {
            f32x4 a0 = A[h][0], a1 = A[h][1];
            ss = fmaf(a0.x, a0.x, ss); ss = fmaf(a0.y, a0.y, ss);
            ss = fmaf(a0.z, a0.z, ss); ss = fmaf(a0.w, a0.w, ss);
            ss = fmaf(a1.x, a1.x, ss); ss = fmaf(a1.y, a1.y, ss);
            ss = fmaf(a1.z, a1.z, ss); ss = fmaf(a1.w, a1.w, ss);
            union { bf16x8 v; unsigned u[4]; } af;
            af.u[0] = cvt_pk(a0.x, a0.y); af.u[1] = cvt_pk(a0.z, a0.w);
            af.u[2] = cvt_pk(a1.x, a1.y); af.u[3] = cvt_pk(a1.z, a1.w);
            #pragma unroll
            for (int n = 0; n < 3; ++n)
                acc[n] = __builtin_amdgcn_mfma_f32_16x16x32_bf16(
                             af.v, Bv[n * 2 + h], acc[n], 0, 0, 0);
        }
    };

    // 2-deep register pipeline, statically named buffers
    f32x4 A0[2][2], A1[2][2];
    bf16x8 B0[6], B1[6];
    loadA(0, A0); loadB(0, B0);
    loadA(1, A1); loadB(1, B1);

    for (int sp = 0; sp < 8; ++sp) {
        const int c = 2 * sp;
        compute(A0, B0);
        if (c + 2 < 16) { loadA(c + 2, A0); loadB(c + 2, B0); }
        compute(A1, B1);
        if (c + 3 < 16) { loadA(c + 3, A1); loadB(c + 3, B1); }
    }

    // ---- reductions & epilogue (proven in round 2) ----
    ss += __shfl_xor(ss, 16);
    ss += __shfl_xor(ss, 32);
    if (lane < 16) ssw[wave][lane] = ss;

    #pragma unroll
    for (int n = 0; n < 3; ++n)
        #pragma unroll
        for (int i = 0; i < 4; ++i)
            dots[wave][kg * 4 + i][n * 16 + rl] = acc[n][i];

    for (int i = tid; i < LTOT * LTOT; i += 256) w2s[i] = w2[i];
    __syncthreads();

    if (tid < 16) {
        float st = ssw[0][tid] + ssw[1][tid] + ssw[2][tid] + ssw[3][tid];
        scl[tid] = rsqrtf(st * (1.0f / (float)DDIM) + 1e-5f);
    }
    __syncthreads();

    #pragma unroll
    for (int i = 0; i < 3; ++i) {
        int v = tid + i * 256;
        int row = v / 48, col = v - row * 48;
        float d = dots[0][row][col] + dots[1][row][col]
                + dots[2][row][col] + dots[3][row][col];
        float h = d * scl[row];
        gbuf[row][col] = h * 0.5f * (1.0f + erff(h * 0.70710678118654752f));
    }
    __syncthreads();

    #pragma unroll
    for (int i = 0; i < 3; ++i) {
        int v = tid + i * 256;
        int row = v / 48, l = v - row * 48;
        float sacc = 0.f;
        #pragma unroll
        for (int k = 0; k < LTOT; ++k)
            sacc = fmaf(gbuf[row][k], w2s[l * LTOT + k], sacc);
        int rg = row0 + row;
        int b  = rg >> 12;
        int t  = rg & 4095;
        int cc = l / 12, j = l - cc * 12;
        out[(((size_t)(cc * 4 + b) * 4096 + t) * 12) + j] = sacc;
    }
}

extern "C" void kernel_launch(void* const* d_in, const int* in_sizes, int n_in,
                              void* d_out, int out_size, void* d_ws, size_t ws_size,
                              hipStream_t stream) {
    const float* x  = (const float*)d_in[0];
    const float* W1 = (const float*)d_in[1];
    const float* W2 = (const float*)d_in[2];
    float* out = (float*)d_out;
    ushort* w1b = (ushort*)d_ws;

    w1cvt_kernel<<<(LTOT * DDIM) / 256, 256, 0, stream>>>(W1, w1b);
    fused_kernel<<<16384 / 16, 256, 0, stream>>>(x, w1b, W2, out);
}